// Round 1
// 974.421 us; speedup vs baseline: 1.0952x; 1.0952x over previous
//
#include <hip/hip_runtime.h>
#include <climits>
#include <cstdint>

// Problem constants (fixed by setup_inputs()).
#define N_ROWS 16384
#define K_DIM  4096
#define O_DIM  4096

typedef __attribute__((ext_vector_type(4))) int int4v;
typedef __attribute__((address_space(1))) void gvoid;
typedef __attribute__((address_space(3))) void svoid;

// ---------------------------------------------------------------------------
// ws layout (byte offsets):
//   0      : u32 scalars[16]
//            [0] x_min_enc  [1] x_max_enc  [2] r_min(i32)  [3] r_max(i32)
//            [4] sc(f32)    [5] zp(f32)    [6] re_sc(f32)  [7] re_zp(f32)
//   256    : w_scale  f32[4096]
//   32768  : corr     i32[4096]   (colsum(qw) first, then qbias - zp*colsum)
//   65536  : qw8      int8[4096*4096]        (16 MiB)
//   65536+16Mi : qx8  int8[16384*4096]       (64 MiB)
// ---------------------------------------------------------------------------

__device__ __forceinline__ unsigned enc_f(float f) {
  unsigned u = __float_as_uint(f);
  return (u & 0x80000000u) ? ~u : (u | 0x80000000u);  // monotone float->uint
}
__device__ __forceinline__ float dec_f(unsigned u) {
  unsigned b = (u & 0x80000000u) ? (u & 0x7FFFFFFFu) : ~u;
  return __uint_as_float(b);
}

__device__ __forceinline__ void gload16(const void* g, void* l) {
  __builtin_amdgcn_global_load_lds((gvoid*)g, (svoid*)l, 16, 0, 0);
}

// compiler fence + hw barrier (no vmcnt/lgkm drain — that's the whole point)
#define BAR()                                  \
  do {                                         \
    asm volatile("" ::: "memory");             \
    __builtin_amdgcn_s_barrier();              \
    asm volatile("" ::: "memory");             \
  } while (0)

#define MFMA_I8(a, b, c) __builtin_amdgcn_mfma_i32_16x16x64_i8(a, b, c, 0, 0, 0)

// --- init the atomic reduction slots (ws is poisoned 0xAA each launch) -----
__global__ void k_init(unsigned* s) {
  s[0] = 0xFFFFFFFFu;          // x min (encoded)
  s[1] = 0u;                   // x max (encoded)
  ((int*)s)[2] = INT_MAX;      // res32 min
  ((int*)s)[3] = INT_MIN;      // res32 max
}

// --- global min/max of x ---------------------------------------------------
__global__ void k_minmax_x(const float4* __restrict__ x, unsigned* s, int n4) {
  const int tid = threadIdx.x;
  float lmn = 3.402823466e38f, lmx = -3.402823466e38f;
  for (int i = blockIdx.x * blockDim.x + tid; i < n4; i += gridDim.x * blockDim.x) {
    float4 v = x[i];
    lmn = fminf(lmn, fminf(fminf(v.x, v.y), fminf(v.z, v.w)));
    lmx = fmaxf(lmx, fmaxf(fmaxf(v.x, v.y), fmaxf(v.z, v.w)));
  }
  __shared__ float smn[256], smx[256];
  smn[tid] = lmn; smx[tid] = lmx;
  __syncthreads();
  for (int st = 128; st > 0; st >>= 1) {
    if (tid < st) {
      smn[tid] = fminf(smn[tid], smn[tid + st]);
      smx[tid] = fmaxf(smx[tid], smx[tid + st]);
    }
    __syncthreads();
  }
  if (tid == 0) {
    atomicMin(&s[0], enc_f(smn[0]));
    atomicMax(&s[1], enc_f(smx[0]));
  }
}

// --- activation quant scalars ---------------------------------------------
__global__ void k_scalar_a(unsigned* s) {
  float mn = fminf(dec_f(s[0]), 0.0f);
  float mx = fmaxf(dec_f(s[1]), 0.0f);
  float sc = (mx - mn) / 255.0f;
  float zp = rintf(-128.0f - mn / sc);
  float* f = (float*)s;
  f[4] = sc;
  f[5] = zp;
}

// --- weight quant: one block per output channel ----------------------------
__global__ void k_wquant(const float* __restrict__ w, char* __restrict__ qw,
                         float* __restrict__ w_scale, int* __restrict__ colsum) {
  const int o = blockIdx.x, tid = threadIdx.x;
  const float4* row = (const float4*)(w + (size_t)o * K_DIM);
  float4 v[4];
  float ma = 0.0f;
#pragma unroll
  for (int i = 0; i < 4; i++) {
    v[i] = row[tid + i * 256];
    ma = fmaxf(ma, fmaxf(fmaxf(fabsf(v[i].x), fabsf(v[i].y)),
                         fmaxf(fabsf(v[i].z), fabsf(v[i].w))));
  }
  __shared__ float red[256];
  red[tid] = ma;
  __syncthreads();
  for (int st = 128; st > 0; st >>= 1) {
    if (tid < st) red[tid] = fmaxf(red[tid], red[tid + st]);
    __syncthreads();
  }
  __shared__ float wsb;
  if (tid == 0) {
    wsb = red[0] / 127.0f;     // w_scale = max|w| / QMAX
    w_scale[o] = wsb;
  }
  __syncthreads();
  const float wsc = wsb;
  uint32_t* qrow = (uint32_t*)(qw + (size_t)o * K_DIM);
  int lsum = 0;
#pragma unroll
  for (int i = 0; i < 4; i++) {
    const float* pv = (const float*)&v[i];
    uint32_t pk = 0;
#pragma unroll
    for (int c = 0; c < 4; c++) {
      float qf = rintf(pv[c] / wsc);            // IEEE div + round-half-even
      qf = fminf(fmaxf(qf, -127.0f), 127.0f);
      int qi = (int)qf;
      lsum += qi;
      pk |= (uint32_t)(unsigned char)(signed char)qi << (8 * c);
    }
    qrow[tid + i * 256] = pk;
  }
  __shared__ int ired[256];
  ired[tid] = lsum;
  __syncthreads();
  for (int st = 128; st > 0; st >>= 1) {
    if (tid < st) ired[tid] += ired[tid + st];
    __syncthreads();
  }
  if (tid == 0) colsum[o] = ired[0];
}

// --- corr[o] = round(bias/(w_scale*sc)) - zp * colsum[o] -------------------
__global__ void k_corr(const float* __restrict__ bias, const float* __restrict__ w_scale,
                       int* corr, const float* __restrict__ s) {
  const int o = blockIdx.x * blockDim.x + threadIdx.x;
  if (o >= O_DIM) return;
  const float sc = s[4];
  const int zp = (int)s[5];
  const int cs = corr[o];
  const float qb = rintf(bias[o] / (w_scale[o] * sc));
  corr[o] = (int)qb - zp * cs;
}

// --- activation quant: qx = clip(round(x/sc)+zp, -128, 127) ----------------
__global__ void k_xquant(const float4* __restrict__ x, uint32_t* __restrict__ qx,
                         const float* __restrict__ s, int n4) {
  const float sc = s[4], zp = s[5];
  for (int i = blockIdx.x * blockDim.x + threadIdx.x; i < n4;
       i += gridDim.x * blockDim.x) {
    float4 v = x[i];
    const float* pv = (const float*)&v;
    uint32_t pk = 0;
#pragma unroll
    for (int c = 0; c < 4; c++) {
      float qf = rintf(pv[c] / sc) + zp;        // IEEE div; clip AFTER +zp
      qf = fminf(fmaxf(qf, -128.0f), 127.0f);
      pk |= (uint32_t)(unsigned char)(signed char)(int)qf << (8 * c);
    }
    qx[i] = pk;
  }
}

// ---------------------------------------------------------------------------
// int8 GEMM, 256x256 tile, 8 waves (2M x 4N), 16x16x64 i8 MFMA.
// Pipeline (T3+T4): 3 LDS buffers (tile t -> buf t%3), BK = 64 bytes.
//   During tile t we stage tile t+2 into buf (t+2)%3 (A half in phase 1,
//   B half in phase 2; 2 x global_load_lds each). End-of-tile wait is
//   s_waitcnt vmcnt(4) (tile t+1 retired, t+2 still in flight) — never a
//   vmcnt(0) drain in steady state. Ledger:
//     * writes to buf (t+2)%3 happen >= 1 full barrier after the last
//       ds_read of that buffer's old data retired (lgkm wait precedes MFMA
//       precedes the inter-tile barrier), so no WAR race;
//     * reads of buf t%3 are guarded by vmcnt(4)+barrier at end of t-1.
// LDS swizzle (T2): phys = a ^ ((a>>3) & 0x30) — involution; fragment reads
//   (row stride 64B) land on all 8 bank quads (2-way residual = free).
//   global_load_lds dest stays LINEAR; the source address is pre-swizzled
//   with the same involution (rule: both-sides-or-neither).
// T5: s_setprio(1) around each 16-MFMA cluster. T1: bijective XCD chunking.
// ---------------------------------------------------------------------------
#define BM 256
#define BN 256
#define BKB 64                 // K-bytes (= i8 elements) per tile
#define NTILE (K_DIM / BKB)    // 64
#define BUFB (BM * BKB)        // 16384 B per operand per buffer

__global__ __launch_bounds__(512, 2) void k_gemm(
    const char* __restrict__ qx, const char* __restrict__ qw,
    int* __restrict__ C, const int* __restrict__ corr, int* rm) {
  __shared__ int4v As[3 * BUFB / 16];   // 48 KiB
  __shared__ int4v Bs[3 * BUFB / 16];   // 48 KiB

  const int tid = threadIdx.x;
  const int lane = tid & 63;
  const int wave = tid >> 6;
  const int q = lane >> 4;        // 0..3   (16B chunk of the 64B K-row)
  const int r_ = lane & 15;       // 0..15  (row within 16x16 fragment)
  const int wm = (wave >> 2) * 128;   // 0 / 128
  const int wn = (wave & 3) * 64;     // 0 / 64 / 128 / 192

  // T1: bijective XCD chunking (1024 wgs, 8 XCDs, 128 contiguous per XCD).
  int wg = blockIdx.y * gridDim.x + blockIdx.x;
  wg = (wg & 7) * 128 + (wg >> 3);
  const long bm = (long)(wg >> 4) * BM;    // N-row of tile
  const long bo = (long)(wg & 15) * BN;    // O-col of tile

  // --- staging addresses: linear LDS dest, swizzle applied to global src ---
  // linear off p = (pass*512 + tid)*16 ; logical a = p ^ ((p>>3)&0x30)
  //   -> row unchanged (tid>>2 + pass*128), col = ((tid&3)^((tid>>3)&3))*16
  const int srow = tid >> 2;                              // 0..127
  const int scol = (((tid & 3) ^ ((tid >> 3) & 3)) << 4); // pre-swizzled col
  const char* gA0 = qx + (bm + srow) * (long)K_DIM + scol;
  const char* gA1 = gA0 + (long)128 * K_DIM;
  const char* gB0 = qw + (bo + srow) * (long)K_DIM + scol;
  const char* gB1 = gB0 + (long)128 * K_DIM;
  char* lA = (char*)As + tid * 16;
  char* lB = (char*)Bs + tid * 16;

  // --- fragment LDS byte offsets (within one buffer), swizzled -------------
  int offA[8], offB[4];
#pragma unroll
  for (int m = 0; m < 8; ++m) {
    const int row = wm + m * 16 + r_;
    const int a = row * 64 + q * 16;
    offA[m] = a ^ (((row >> 1) & 3) << 4);
  }
#pragma unroll
  for (int n = 0; n < 4; ++n) {
    const int row = wn + n * 16 + r_;
    const int a = row * 64 + q * 16;
    offB[n] = a ^ (((row >> 1) & 3) << 4);
  }

  int4v acc[8][4];
#pragma unroll
  for (int m = 0; m < 8; ++m)
#pragma unroll
    for (int n = 0; n < 4; ++n) acc[m][n] = (int4v){0, 0, 0, 0};

  // --- prologue: stage tile 0 -> buf 0, tile 1 -> buf 1 --------------------
  gload16(gA0, lA);
  gload16(gA1, lA + 8192);
  gload16(gB0, lB);
  gload16(gB1, lB + 8192);
  gload16(gA0 + 64, lA + BUFB);
  gload16(gA1 + 64, lA + BUFB + 8192);
  gload16(gB0 + 64, lB + BUFB);
  gload16(gB1 + 64, lB + BUFB + 8192);
  asm volatile("s_waitcnt vmcnt(4)" ::: "memory");  // tile 0 landed
  __builtin_amdgcn_s_barrier();
  asm volatile("" ::: "memory");

  int cur = 0;
  int gk = 128;                                      // k-offset of tile t+2
  for (int t = 0; t < NTILE; ++t) {
    const char* bA = (const char*)As + cur * BUFB;
    const char* bB = (const char*)Bs + cur * BUFB;
    int nxt = cur + 2;
    if (nxt >= 3) nxt -= 3;

    int4v af[4], bf[4];
    // ---- phase 1: A-frags 0..3 + all B-frags; stage next-next A ----------
#pragma unroll
    for (int m = 0; m < 4; ++m) af[m] = *(const int4v*)(bA + offA[m]);
#pragma unroll
    for (int n = 0; n < 4; ++n) bf[n] = *(const int4v*)(bB + offB[n]);
    if (t < NTILE - 2) {
      char* dA = (char*)As + nxt * BUFB + tid * 16;
      gload16(gA0 + gk, dA);
      gload16(gA1 + gk, dA + 8192);
    }
    BAR();
    __builtin_amdgcn_s_setprio(1);
#pragma unroll
    for (int m = 0; m < 4; ++m)
#pragma unroll
      for (int n = 0; n < 4; ++n)
        acc[m][n] = MFMA_I8(af[m], bf[n], acc[m][n]);
    __builtin_amdgcn_s_setprio(0);
    BAR();

    // ---- phase 2: A-frags 4..7; stage next-next B -------------------------
#pragma unroll
    for (int m = 0; m < 4; ++m) af[m] = *(const int4v*)(bA + offA[4 + m]);
    if (t < NTILE - 2) {
      char* dB = (char*)Bs + nxt * BUFB + tid * 16;
      gload16(gB0 + gk, dB);
      gload16(gB1 + gk, dB + 8192);
    }
    BAR();
    __builtin_amdgcn_s_setprio(1);
#pragma unroll
    for (int m = 0; m < 4; ++m)
#pragma unroll
      for (int n = 0; n < 4; ++n)
        acc[4 + m][n] = MFMA_I8(af[m], bf[n], acc[4 + m][n]);
    __builtin_amdgcn_s_setprio(0);
    // counted wait: tile t+1 must be resident; t+2 stays in flight.
    if (t < NTILE - 2) {
      asm volatile("s_waitcnt vmcnt(4)" ::: "memory");
    } else if (t == NTILE - 2) {
      asm volatile("s_waitcnt vmcnt(0)" ::: "memory");
    }
    __builtin_amdgcn_s_barrier();
    asm volatile("" ::: "memory");

    cur = cur == 2 ? 0 : cur + 1;
    gk += 64;
  }

  // --- epilogue: add corr, store res32, track block min/max ----------------
  int lmin = INT_MAX, lmax = INT_MIN;
#pragma unroll
  for (int n = 0; n < 4; ++n) {
    const int col = (int)bo + wn + n * 16 + r_;
    const int cr = corr[col];
#pragma unroll
    for (int m = 0; m < 8; ++m) {
#pragma unroll
      for (int rr = 0; rr < 4; ++rr) {
        const long row = bm + wm + m * 16 + q * 4 + rr;  // C/D: row=q*4+reg
        const int v = acc[m][n][rr] + cr;
        C[row * O_DIM + col] = v;
        lmin = min(lmin, v);
        lmax = max(lmax, v);
      }
    }
  }
  __syncthreads();   // all LDS reads of the K-loop are long retired
  int* red = (int*)As;
  red[tid] = lmin;
  red[512 + tid] = lmax;
  __syncthreads();
  for (int st = 256; st > 0; st >>= 1) {
    if (tid < st) {
      red[tid] = min(red[tid], red[tid + st]);
      red[512 + tid] = max(red[512 + tid], red[512 + tid + st]);
    }
    __syncthreads();
  }
  if (tid == 0) {
    atomicMin(&rm[2], red[0]);
    atomicMax(&rm[3], red[512]);
  }
}

// --- requant scalars -------------------------------------------------------
__global__ void k_scalar_b(unsigned* s) {
  float rmn = fminf((float)((int*)s)[2], 0.0f);  // res32 < 2^24: exact
  float rmx = fmaxf((float)((int*)s)[3], 0.0f);
  float re_sc = (rmx - rmn) / 255.0f;
  float re_zp = rintf(-128.0f - rmn / re_sc);
  float* f = (float*)s;
  f[6] = re_sc;
  f[7] = re_zp;
}

// --- final requant + dequant, in place over d_out --------------------------
__global__ void k_requant(int4* ci, float4* co, const float* __restrict__ w_scale,
                          const float* __restrict__ s, int n4) {
  const float sc = s[4], re_sc = s[6], re_zp = s[7];
  const float4* wsv4 = (const float4*)w_scale;
  for (int i = blockIdx.x * blockDim.x + threadIdx.x; i < n4;
       i += gridDim.x * blockDim.x) {
    int4 r = ci[i];
    float4 wv = wsv4[i & (O_DIM / 4 - 1)];
    float4 o;
    {
      float v = rintf((float)r.x / re_sc) + re_zp;
      v = fminf(fmaxf(v, -128.0f), 127.0f);
      o.x = (v - re_zp) * ((sc * wv.x) * re_sc);
    }
    {
      float v = rintf((float)r.y / re_sc) + re_zp;
      v = fminf(fmaxf(v, -128.0f), 127.0f);
      o.y = (v - re_zp) * ((sc * wv.y) * re_sc);
    }
    {
      float v = rintf((float)r.z / re_sc) + re_zp;
      v = fminf(fmaxf(v, -128.0f), 127.0f);
      o.z = (v - re_zp) * ((sc * wv.z) * re_sc);
    }
    {
      float v = rintf((float)r.w / re_sc) + re_zp;
      v = fminf(fmaxf(v, -128.0f), 127.0f);
      o.w = (v - re_zp) * ((sc * wv.w) * re_sc);
    }
    co[i] = o;
  }
}

extern "C" void kernel_launch(void* const* d_in, const int* in_sizes, int n_in,
                              void* d_out, int out_size, void* d_ws, size_t ws_size,
                              hipStream_t stream) {
  const float* x = (const float*)d_in[0];
  const float* w = (const float*)d_in[1];
  const float* bias = (const float*)d_in[2];

  char* ws = (char*)d_ws;
  unsigned* s = (unsigned*)ws;
  float* w_scale = (float*)(ws + 256);
  int* corr = (int*)(ws + 32768);
  char* qw = ws + 65536;
  char* qx = ws + 65536 + (size_t)O_DIM * K_DIM;

  const int n4x = (N_ROWS * K_DIM) / 4;

  k_init<<<1, 1, 0, stream>>>(s);
  k_minmax_x<<<2048, 256, 0, stream>>>((const float4*)x, s, n4x);
  k_scalar_a<<<1, 1, 0, stream>>>(s);
  k_wquant<<<O_DIM, 256, 0, stream>>>(w, qw, w_scale, corr);
  k_corr<<<O_DIM / 256, 256, 0, stream>>>(bias, w_scale, corr, (const float*)s);
  k_xquant<<<2048, 256, 0, stream>>>((const float4*)x, (uint32_t*)qx,
                                     (const float*)s, n4x);
  dim3 g(O_DIM / BN, N_ROWS / BM);   // 16 x 64 = 1024 wgs
  k_gemm<<<g, 512, 0, stream>>>(qx, qw, (int*)d_out, corr, (int*)s);
  k_scalar_b<<<1, 1, 0, stream>>>(s);
  k_requant<<<4096, 256, 0, stream>>>((int4*)d_out, (float4*)d_out, w_scale,
                                      (const float*)s, (N_ROWS * O_DIM) / 4);
}